// Round 8
// baseline (95.660 us; speedup 1.0000x reference)
//
#include <hip/hip_runtime.h>
#include <hip/hip_bf16.h>

// NT-Xent loss, N=4096, Z=128, T=0.5.
//
// Round 4: scratch matrix in MFMA-FRAGMENT ORDER -> coalesced dwordx4
// fragment loads. Round 7: 64-row waves (A-frags persist) -> 23.4 us, but
// grid-limited to 2 waves/SIMD: MFMA and exp2-epilogue VALU can't overlap.
// Round 8: FP8 E4M3 storage + v_mfma_f32_16x16x32_fp8_fp8 (i64 operands,
// 2 VGPRs per frag). Halves fragment regs (afrag 64->32) and VMEM bytes ->
// ~110 regs -> 4 waves/SIMD, grid 1024 = 4 blocks/CU = 16 waves/CU.
// Accuracy: e4m3 ~3.6% rms elem err -> ~0.009 rms in sim/T -> ~1e-3 loss
// err, threshold 0.18. Positives remain exact fp32. Within-lane k-order of
// the pack cancels in A*A^T (same map on both operands).
//
// fp8 pack layout (16 B granules, two k-chunks per granule):
//   byte(r, k) = ((r>>4)*2 + (k>>6))*1024 + ((k>>3)&3)*256 + (r&15)*16
//                + ((k>>5)&1)*8 + (k&7)
// A/B fragment load for rowgroup G, ks2: dwordx4 at (G*2+ks2)*1024 + lane*16
// (1 KB/wave, contiguous); .x = k-half 0, .y = k-half 1 of the i64 pair.

#define N_PAIRS 4096
#define ZDIM    128
#define NROWS   8192
#define QS 1.6986437717f   // sqrt(2 * log2(e)) ; folds 1/T=2 and exp->exp2

typedef float floatx4 __attribute__((ext_vector_type(4)));
typedef long  longx2  __attribute__((ext_vector_type(2)));

__global__ __launch_bounds__(256) void k_normalize(
    const float* __restrict__ z1, const float* __restrict__ z2,
    char* __restrict__ pack, float* __restrict__ pos,
    float* __restrict__ denom)
{
    const int zi = blockIdx.x * 256 + threadIdx.x;   // grid 1024 blocks; 32 zero denom
    if (zi < NROWS) denom[zi] = 0.0f;

    const int w = threadIdx.x >> 6;
    const int lane = threadIdx.x & 63;
    const int p = blockIdx.x * 4 + w;            // pair index, < 4096
    const float2 a = ((const float2*)(z1 + (size_t)p * ZDIM))[lane];
    const float2 b = ((const float2*)(z2 + (size_t)p * ZDIM))[lane];
    float s1 = a.x * a.x + a.y * a.y;
    float s2 = b.x * b.x + b.y * b.y;
    float d  = a.x * b.x + a.y * b.y;
    #pragma unroll
    for (int off = 1; off < 64; off <<= 1) {
        s1 += __shfl_xor(s1, off, 64);
        s2 += __shfl_xor(s2, off, 64);
        d  += __shfl_xor(d,  off, 64);
    }
    const float n1 = fmaxf(sqrtf(s1), 1e-8f);
    const float n2 = fmaxf(sqrtf(s2), 1e-8f);
    const float i1 = 1.0f / n1, i2 = 1.0f / n2;
    const float q1 = i1 * QS, q2 = i2 * QS;

    // lane holds k0 = 2*lane, k0+1 of its row:
    //   ks2 = lane>>5 ; half = (lane>>4)&1 ; q = (lane>>2)&3 ; j = (lane&3)*2
    const int ks2  = lane >> 5;
    const int half = (lane >> 4) & 1;
    const int qq   = (lane >> 2) & 3;
    const int jj   = (lane & 3) * 2;
    const int r1 = p, r2 = p + N_PAIRS;
    const size_t o1 = ((size_t)((r1 >> 4) * 2 + ks2)) * 1024 + qq * 256
                    + (r1 & 15) * 16 + half * 8 + jj;
    const size_t o2 = ((size_t)((r2 >> 4) * 2 + ks2)) * 1024 + qq * 256
                    + (r2 & 15) * 16 + half * 8 + jj;
    const int pk1 = __builtin_amdgcn_cvt_pk_fp8_f32(a.x * q1, a.y * q1, 0, false);
    const int pk2 = __builtin_amdgcn_cvt_pk_fp8_f32(b.x * q2, b.y * q2, 0, false);
    *(unsigned short*)(pack + o1) = (unsigned short)pk1;
    *(unsigned short*)(pack + o2) = (unsigned short)pk2;
    if (lane == 0) pos[p] = d * i1 * i2;
}

// Block: 256 thr = 4 waves stacked vertically; wave w owns 64 rows
// [rt*256 + w*64, +64). Block tile 256 rows x 256-col slab, swept in 8
// steps of 32 cols (acc[4][2]). Grid = 32 rt x 32 cs = 1024 blocks
// = 4 blocks/CU = 16 waves/CU (4/SIMD at ~110 regs).
__global__ __launch_bounds__(256) void k_simsum(
    const char* __restrict__ pack, float* __restrict__ denom)
{
    const int tid  = threadIdx.x;
    const int lane = tid & 63;
    const int w    = tid >> 6;
    const int rt   = blockIdx.x >> 5;   // row tile [0,32)
    const int cs   = blockIdx.x & 31;   // col slab [0,32)
    const int q    = lane >> 4;         // quad 0..3
    const int l16  = lane & 15;

    // ---- persistent A fragments: wave's 64 rows x full K=128 (32 VGPRs) ----
    const int rowb = rt * 256 + w * 64;
    const char* Abase = pack + (size_t)(rowb >> 4) * 2048 + lane * 16;
    longx2 afrag[4][2];                  // [mt][ks2]
    #pragma unroll
    for (int mt = 0; mt < 4; ++mt)
        #pragma unroll
        for (int ks2 = 0; ks2 < 2; ++ks2)
            afrag[mt][ks2] = *(const longx2*)(Abase + mt * 2048 + ks2 * 1024);

    float rowsum[4][4];                  // [mt][r]
    #pragma unroll
    for (int mt = 0; mt < 4; ++mt)
        #pragma unroll
        for (int r = 0; r < 4; ++r) rowsum[mt][r] = 0.0f;

    const char* Bcol0 = pack + (size_t)(cs * 16) * 2048 + lane * 16;

    for (int hs = 0; hs < 8; ++hs) {
        // B frags for this 32-col step: [nt][ks2], 4 coalesced dwordx4 loads
        longx2 bfrag[2][2];
        const char* bp = Bcol0 + (size_t)hs * 4096;
        #pragma unroll
        for (int ks2 = 0; ks2 < 2; ++ks2)
            #pragma unroll
            for (int nt = 0; nt < 2; ++nt)
                bfrag[nt][ks2] = *(const longx2*)(bp + nt * 2048 + ks2 * 1024);

        floatx4 acc[4][2];
        #pragma unroll
        for (int mt = 0; mt < 4; ++mt)
            #pragma unroll
            for (int nt = 0; nt < 2; ++nt) {
                acc[mt][nt].x = 0.f; acc[mt][nt].y = 0.f;
                acc[mt][nt].z = 0.f; acc[mt][nt].w = 0.f;
            }
        #pragma unroll
        for (int ks2 = 0; ks2 < 2; ++ks2) {
            #pragma unroll
            for (int mt = 0; mt < 4; ++mt)
                #pragma unroll
                for (int nt = 0; nt < 2; ++nt)
                    acc[mt][nt] = __builtin_amdgcn_mfma_f32_16x16x32_fp8_fp8(
                        afrag[mt][ks2].x, bfrag[nt][ks2].x, acc[mt][nt], 0, 0, 0);
            #pragma unroll
            for (int mt = 0; mt < 4; ++mt)
                #pragma unroll
                for (int nt = 0; nt < 2; ++nt)
                    acc[mt][nt] = __builtin_amdgcn_mfma_f32_16x16x32_fp8_fp8(
                        afrag[mt][ks2].y, bfrag[nt][ks2].y, acc[mt][nt], 0, 0, 0);
        }

        // ---- fused epilogue: bare exp2 + row-sum ----
        // C/D layout: col = l16, row = q*4 + r (m89/m91, dtype-independent)
        const int colb = cs * 256 + hs * 32;
        #pragma unroll
        for (int mt = 0; mt < 4; ++mt) {
            const int rowtb = rowb + mt * 16;
            #pragma unroll
            for (int nt = 0; nt < 2; ++nt) {
                const int coltb = colb + nt * 16;
                if (rowtb == coltb) {        // wave-uniform: diagonal tile
                    #pragma unroll
                    for (int r = 0; r < 4; ++r) {
                        const float e = __builtin_amdgcn_exp2f(acc[mt][nt][r]);
                        rowsum[mt][r] += (l16 == q * 4 + r) ? 0.0f : e;
                    }
                } else {
                    #pragma unroll
                    for (int r = 0; r < 4; ++r)
                        rowsum[mt][r] += __builtin_amdgcn_exp2f(acc[mt][nt][r]);
                }
            }
        }
    }

    // ---- row-sum reduction: across the 16 lanes holding the same row ----
    #pragma unroll
    for (int mt = 0; mt < 4; ++mt)
        #pragma unroll
        for (int r = 0; r < 4; ++r) {
            float s = rowsum[mt][r];
            s += __shfl_xor(s, 1, 64);
            s += __shfl_xor(s, 2, 64);
            s += __shfl_xor(s, 4, 64);
            s += __shfl_xor(s, 8, 64);
            rowsum[mt][r] = s;
        }
    if (l16 == 0) {
        #pragma unroll
        for (int mt = 0; mt < 4; ++mt)
            #pragma unroll
            for (int r = 0; r < 4; ++r) {
                const int grow = rowb + mt * 16 + q * 4 + r;
                atomicAdd(&denom[grow], rowsum[mt][r]);
            }
    }
}

__global__ __launch_bounds__(1024) void k_finish(
    const float* __restrict__ denom, const float* __restrict__ pos,
    float* __restrict__ out)
{
    __shared__ float red[16];
    const int t = threadIdx.x;
    const int lane = t & 63, wv = t >> 6;
    float s = 0.0f;
    for (int i = t; i < NROWS; i += 1024) s += __logf(denom[i]);
    float p = 0.0f;
    for (int i = t; i < N_PAIRS; i += 1024) p += pos[i];
    float v = s - 4.0f * p;   // sum_i pos_i/T over 2N rows = 4 * sum_p cos_p
    #pragma unroll
    for (int off = 1; off < 64; off <<= 1) v += __shfl_xor(v, off, 64);
    if (lane == 0) red[wv] = v;
    __syncthreads();
    if (wv == 0) {
        float x = (lane < 16) ? red[lane] : 0.0f;
        #pragma unroll
        for (int off = 1; off < 16; off <<= 1) x += __shfl_xor(x, off, 64);
        if (lane == 0) out[0] = x / (float)NROWS;
    }
}

extern "C" void kernel_launch(void* const* d_in, const int* in_sizes, int n_in,
                              void* d_out, int out_size, void* d_ws, size_t ws_size,
                              hipStream_t stream) {
    const float* z1 = (const float*)d_in[0];
    const float* z2 = (const float*)d_in[1];
    float* out = (float*)d_out;

    char* ws = (char*)d_ws;
    char* pack = ws;                                           // 1 MB (fp8)
    float* denom = (float*)(ws + (size_t)NROWS * ZDIM);        // 32 KB
    float* pos   = denom + NROWS;                              // 16 KB

    k_normalize<<<N_PAIRS / 4, 256, 0, stream>>>(z1, z2, pack, pos, denom);
    k_simsum<<<1024, 256, 0, stream>>>(pack, denom);
    k_finish<<<1, 1024, 0, stream>>>(denom, pos, out);
}

// Round 9
// 95.335 us; speedup vs baseline: 1.0034x; 1.0034x over previous
//
#include <hip/hip_runtime.h>
#include <hip/hip_bf16.h>

// NT-Xent loss, N=4096, Z=128, T=0.5.
//
// Round 4: scratch in MFMA-FRAGMENT ORDER -> coalesced dwordx4 frag loads.
// Round 7 (best bf16, 23.4us): 64-row waves + register double-buffered B
// prefetch; limited to 2 waves/SIMD by ~190 regs.
// Round 8 (fp8, regressed): kept fp8 but DROPPED the double-buffer ->
// per-step serial load-stall -> compute -> epilogue chain; occupancy can't
// hide a chain that's mostly stall. Lesson: the prefetch structure, not
// dtype, carried r7.
// Round 9: fp8 E4M3 *with* r7's double-buffered pipeline. afrag 32 regs,
// bufA/bufB 16+16, acc 32, rowsum 16 -> ~130 regs -> 3-4 waves/SIMD at
// grid 1024 = 4 blocks/CU; fp8 also halves fragment VMEM bytes.
//
// fp8 pack layout (16 B granules, two k-chunks per granule):
//   byte(r, k) = ((r>>4)*2 + (k>>6))*1024 + ((k>>3)&3)*256 + (r&15)*16
//                + ((k>>5)&1)*8 + (k&7)
// Fragment load for rowgroup G, ks2: dwordx4 at (G*2+ks2)*1024 + lane*16
// (1 KB/wave, contiguous); .x/.y = the two 32-wide k-halves (i64 operands).
// Any consistent within-lane k-permutation cancels in A*A^T.

#define N_PAIRS 4096
#define ZDIM    128
#define NROWS   8192
#define QS 1.6986437717f   // sqrt(2 * log2(e)) ; folds 1/T=2 and exp->exp2

typedef float floatx4 __attribute__((ext_vector_type(4)));
typedef long  longx2  __attribute__((ext_vector_type(2)));

__global__ __launch_bounds__(256) void k_normalize(
    const float* __restrict__ z1, const float* __restrict__ z2,
    char* __restrict__ pack, float* __restrict__ pos,
    float* __restrict__ denom)
{
    const int zi = blockIdx.x * 256 + threadIdx.x;   // grid 1024 blocks; 32 zero denom
    if (zi < NROWS) denom[zi] = 0.0f;

    const int w = threadIdx.x >> 6;
    const int lane = threadIdx.x & 63;
    const int p = blockIdx.x * 4 + w;            // pair index, < 4096
    const float2 a = ((const float2*)(z1 + (size_t)p * ZDIM))[lane];
    const float2 b = ((const float2*)(z2 + (size_t)p * ZDIM))[lane];
    float s1 = a.x * a.x + a.y * a.y;
    float s2 = b.x * b.x + b.y * b.y;
    float d  = a.x * b.x + a.y * b.y;
    #pragma unroll
    for (int off = 1; off < 64; off <<= 1) {
        s1 += __shfl_xor(s1, off, 64);
        s2 += __shfl_xor(s2, off, 64);
        d  += __shfl_xor(d,  off, 64);
    }
    const float n1 = fmaxf(sqrtf(s1), 1e-8f);
    const float n2 = fmaxf(sqrtf(s2), 1e-8f);
    const float i1 = 1.0f / n1, i2 = 1.0f / n2;
    const float q1 = i1 * QS, q2 = i2 * QS;

    // lane holds k0 = 2*lane, k0+1 of its row:
    //   ks2 = lane>>5 ; half = (lane>>4)&1 ; q = (lane>>2)&3 ; j = (lane&3)*2
    const int ks2  = lane >> 5;
    const int half = (lane >> 4) & 1;
    const int qq   = (lane >> 2) & 3;
    const int jj   = (lane & 3) * 2;
    const int r1 = p, r2 = p + N_PAIRS;
    const size_t o1 = ((size_t)((r1 >> 4) * 2 + ks2)) * 1024 + qq * 256
                    + (r1 & 15) * 16 + half * 8 + jj;
    const size_t o2 = ((size_t)((r2 >> 4) * 2 + ks2)) * 1024 + qq * 256
                    + (r2 & 15) * 16 + half * 8 + jj;
    const int pk1 = __builtin_amdgcn_cvt_pk_fp8_f32(a.x * q1, a.y * q1, 0, false);
    const int pk2 = __builtin_amdgcn_cvt_pk_fp8_f32(b.x * q2, b.y * q2, 0, false);
    *(unsigned short*)(pack + o1) = (unsigned short)pk1;
    *(unsigned short*)(pack + o2) = (unsigned short)pk2;
    if (lane == 0) pos[p] = d * i1 * i2;
}

// Block: 256 thr = 4 waves stacked vertically; wave w owns 64 rows
// [rt*256 + w*64, +64). Block tile 256 rows x 256 cols, swept in 8 steps
// of 32 cols (acc[4][2]) with REGISTER-DOUBLE-BUFFERED B (next-step
// prefetch). Grid = 32 rt x 32 cs = 1024 blocks = 4 blocks/CU.
__global__ __launch_bounds__(256) void k_simsum(
    const char* __restrict__ pack, float* __restrict__ denom)
{
    const int tid  = threadIdx.x;
    const int lane = tid & 63;
    const int w    = tid >> 6;
    const int rt   = blockIdx.x >> 5;   // row tile [0,32)
    const int cs   = blockIdx.x & 31;   // col slab [0,32)
    const int q    = lane >> 4;         // quad 0..3
    const int l16  = lane & 15;

    // ---- persistent A fragments: wave's 64 rows x full K=128 (32 VGPRs) ----
    const int rowb = rt * 256 + w * 64;
    const char* Abase = pack + (size_t)(rowb >> 4) * 2048 + lane * 16;
    longx2 afrag[4][2];                  // [mt][ks2]
    #pragma unroll
    for (int mt = 0; mt < 4; ++mt)
        #pragma unroll
        for (int ks2 = 0; ks2 < 2; ++ks2)
            afrag[mt][ks2] = *(const longx2*)(Abase + mt * 2048 + ks2 * 1024);

    float rowsum[4][4];                  // [mt][r]
    #pragma unroll
    for (int mt = 0; mt < 4; ++mt)
        #pragma unroll
        for (int r = 0; r < 4; ++r) rowsum[mt][r] = 0.0f;

    const char* Bcol0 = pack + (size_t)(cs * 16) * 2048 + lane * 16;

    auto loadB = [&](longx2 (&buf)[2][2], int hs) {
        const char* bp = Bcol0 + (size_t)hs * 4096;
        #pragma unroll
        for (int ks2 = 0; ks2 < 2; ++ks2)
            #pragma unroll
            for (int nt = 0; nt < 2; ++nt)
                buf[nt][ks2] = *(const longx2*)(bp + nt * 2048 + ks2 * 1024);
    };

    auto compute = [&](longx2 (&buf)[2][2], int hs) {
        floatx4 acc[4][2];
        #pragma unroll
        for (int mt = 0; mt < 4; ++mt)
            #pragma unroll
            for (int nt = 0; nt < 2; ++nt) {
                acc[mt][nt].x = 0.f; acc[mt][nt].y = 0.f;
                acc[mt][nt].z = 0.f; acc[mt][nt].w = 0.f;
            }
        #pragma unroll
        for (int ks2 = 0; ks2 < 2; ++ks2) {
            #pragma unroll
            for (int mt = 0; mt < 4; ++mt)
                #pragma unroll
                for (int nt = 0; nt < 2; ++nt)
                    acc[mt][nt] = __builtin_amdgcn_mfma_f32_16x16x32_fp8_fp8(
                        afrag[mt][ks2].x, buf[nt][ks2].x, acc[mt][nt], 0, 0, 0);
            #pragma unroll
            for (int mt = 0; mt < 4; ++mt)
                #pragma unroll
                for (int nt = 0; nt < 2; ++nt)
                    acc[mt][nt] = __builtin_amdgcn_mfma_f32_16x16x32_fp8_fp8(
                        afrag[mt][ks2].y, buf[nt][ks2].y, acc[mt][nt], 0, 0, 0);
        }
        // fused epilogue: bare exp2 + row-sum.
        // C/D layout: col = l16, row = q*4 + r (m89/m91, dtype-independent)
        const int colb = cs * 256 + hs * 32;
        #pragma unroll
        for (int mt = 0; mt < 4; ++mt) {
            const int rowtb = rowb + mt * 16;
            #pragma unroll
            for (int nt = 0; nt < 2; ++nt) {
                const int coltb = colb + nt * 16;
                if (rowtb == coltb) {        // wave-uniform: diagonal tile
                    #pragma unroll
                    for (int r = 0; r < 4; ++r) {
                        const float e = __builtin_amdgcn_exp2f(acc[mt][nt][r]);
                        rowsum[mt][r] += (l16 == q * 4 + r) ? 0.0f : e;
                    }
                } else {
                    #pragma unroll
                    for (int r = 0; r < 4; ++r)
                        rowsum[mt][r] += __builtin_amdgcn_exp2f(acc[mt][nt][r]);
                }
            }
        }
    };

    // ---- main sweep: 8 steps of 32 cols, register-double-buffered B ----
    longx2 bufA[2][2], bufB[2][2];
    loadB(bufA, 0);
    for (int hs = 0; hs < 8; hs += 2) {
        loadB(bufB, hs + 1);
        compute(bufA, hs);
        loadB(bufA, (hs + 2) & 7);     // wrap on last iter: valid mem, unused
        compute(bufB, hs + 1);
    }

    // ---- row-sum reduction: across the 16 lanes holding the same row ----
    #pragma unroll
    for (int mt = 0; mt < 4; ++mt)
        #pragma unroll
        for (int r = 0; r < 4; ++r) {
            float s = rowsum[mt][r];
            s += __shfl_xor(s, 1, 64);
            s += __shfl_xor(s, 2, 64);
            s += __shfl_xor(s, 4, 64);
            s += __shfl_xor(s, 8, 64);
            rowsum[mt][r] = s;
        }
    if (l16 == 0) {
        #pragma unroll
        for (int mt = 0; mt < 4; ++mt)
            #pragma unroll
            for (int r = 0; r < 4; ++r) {
                const int grow = rowb + mt * 16 + q * 4 + r;
                atomicAdd(&denom[grow], rowsum[mt][r]);
            }
    }
}

__global__ __launch_bounds__(1024) void k_finish(
    const float* __restrict__ denom, const float* __restrict__ pos,
    float* __restrict__ out)
{
    __shared__ float red[16];
    const int t = threadIdx.x;
    const int lane = t & 63, wv = t >> 6;
    float s = 0.0f;
    for (int i = t; i < NROWS; i += 1024) s += __logf(denom[i]);
    float p = 0.0f;
    for (int i = t; i < N_PAIRS; i += 1024) p += pos[i];
    float v = s - 4.0f * p;   // sum_i pos_i/T over 2N rows = 4 * sum_p cos_p
    #pragma unroll
    for (int off = 1; off < 64; off <<= 1) v += __shfl_xor(v, off, 64);
    if (lane == 0) red[wv] = v;
    __syncthreads();
    if (wv == 0) {
        float x = (lane < 16) ? red[lane] : 0.0f;
        #pragma unroll
        for (int off = 1; off < 16; off <<= 1) x += __shfl_xor(x, off, 64);
        if (lane == 0) out[0] = x / (float)NROWS;
    }
}

extern "C" void kernel_launch(void* const* d_in, const int* in_sizes, int n_in,
                              void* d_out, int out_size, void* d_ws, size_t ws_size,
                              hipStream_t stream) {
    const float* z1 = (const float*)d_in[0];
    const float* z2 = (const float*)d_in[1];
    float* out = (float*)d_out;

    char* ws = (char*)d_ws;
    char* pack = ws;                                           // 1 MB (fp8)
    float* denom = (float*)(ws + (size_t)NROWS * ZDIM);        // 32 KB
    float* pos   = denom + NROWS;                              // 16 KB

    k_normalize<<<N_PAIRS / 4, 256, 0, stream>>>(z1, z2, pack, pos, denom);
    k_simsum<<<1024, 256, 0, stream>>>(pack, denom);
    k_finish<<<1, 1024, 0, stream>>>(denom, pos, out);
}

// Round 10
// 83.987 us; speedup vs baseline: 1.1390x; 1.1351x over previous
//
#include <hip/hip_runtime.h>
#include <hip/hip_bf16.h>

// NT-Xent loss, N=4096, Z=128, T=0.5.
//
// Round 4: scratch in MFMA-FRAGMENT ORDER -> coalesced dwordx4 frag loads.
// Round 7 (best, 23.4us k_simsum): bf16, 64-row waves (persistent A-frags),
// 512 blocks = 2/CU, register double-buffered B.
// Rounds 8/9 (fp8): regressed to ~35us with AND without double-buffering --
// unexplained by the visible counters; direction abandoned, bf16 restored.
// Round 10: r7 + SOFTWARE-PIPELINED EPILOGUE. Two accumulator sets: step s's
// exp2/row-sum VALU issues while step s+1's 32-MFMA batch occupies the
// matrix pipe (no data dependency between them), hiding the epilogue and
// the last-MFMA latency bubble. ~225 regs -> still 2 waves/SIMD, no spill.
//
// pack layout (16 B granules): pack[(G*4+ks)*64 + q*16 + n] = rows G*16+n,
// k in [ks*32+q*8, +8)  -> A/B frag load = dwordx4 at (G*4+ks)*512 + lane*8.
//
//  k_normalize: row-normalize (fp32), quantize bf16 scaled by
//               QS = sqrt(2*log2(e)) (folds 1/T=2 and exp->exp2), write in
//               fragment order; exact fp32 pair-cosines pos[4096]; zero denom.
//  k_simsum:    denom[i] = sum_{j!=i} exp(2*sim_ij), full matrix.
//  k_finish:    out = (sum_i log denom_i - 4 * sum_p pos_p) / 8192

#define N_PAIRS 4096
#define ZDIM    128
#define NROWS   8192
#define QS 1.6986437717f   // sqrt(2 * log2(e))

typedef __bf16 bf16x8 __attribute__((ext_vector_type(8)));
typedef float  floatx4 __attribute__((ext_vector_type(4)));

__global__ __launch_bounds__(256) void k_normalize(
    const float* __restrict__ z1, const float* __restrict__ z2,
    __hip_bfloat16* __restrict__ pack, float* __restrict__ pos,
    float* __restrict__ denom)
{
    const int zi = blockIdx.x * 256 + threadIdx.x;   // grid 1024 blocks; 32 zero denom
    if (zi < NROWS) denom[zi] = 0.0f;

    const int w = threadIdx.x >> 6;
    const int lane = threadIdx.x & 63;
    const int p = blockIdx.x * 4 + w;            // pair index, < 4096
    const float2 a = ((const float2*)(z1 + (size_t)p * ZDIM))[lane];
    const float2 b = ((const float2*)(z2 + (size_t)p * ZDIM))[lane];
    float s1 = a.x * a.x + a.y * a.y;
    float s2 = b.x * b.x + b.y * b.y;
    float d  = a.x * b.x + a.y * b.y;
    #pragma unroll
    for (int off = 1; off < 64; off <<= 1) {
        s1 += __shfl_xor(s1, off, 64);
        s2 += __shfl_xor(s2, off, 64);
        d  += __shfl_xor(d,  off, 64);
    }
    const float n1 = fmaxf(sqrtf(s1), 1e-8f);
    const float n2 = fmaxf(sqrtf(s2), 1e-8f);
    const float i1 = 1.0f / n1, i2 = 1.0f / n2;
    const float q1 = i1 * QS, q2 = i2 * QS;
    float2 na; na.x = a.x * q1; na.y = a.y * q1;
    float2 nb; nb.x = b.x * q2; nb.y = b.y * q2;

    // lane holds elements e0=2*lane, e0+1 of its row:
    //   ks = lane>>4 ; q = (lane>>2)&3 ; j = (lane&3)*2
    // pack elem idx for row r: ((r>>4)*4 + ks)*512 + q*128 + (r&15)*8 + j
    const int ks = lane >> 4;
    const int qq = (lane >> 2) & 3;
    const int jj = (lane & 3) * 2;
    const int r1 = p, r2 = p + N_PAIRS;
    const size_t i1e = ((size_t)((r1 >> 4) * 4 + ks)) * 512 + qq * 128 + (r1 & 15) * 8 + jj;
    const size_t i2e = ((size_t)((r2 >> 4) * 4 + ks)) * 512 + qq * 128 + (r2 & 15) * 8 + jj;
    *(__hip_bfloat162*)(pack + i1e) = __float22bfloat162_rn(na);
    *(__hip_bfloat162*)(pack + i2e) = __float22bfloat162_rn(nb);
    if (lane == 0) pos[p] = d * i1 * i2;
}

// Block: 256 thr = 4 waves stacked vertically; wave w owns 64 rows
// [rt*256 + w*64, +64). Block tile 256 rows x 512 cols, swept in 16
// half-steps of 32 cols. Grid = 32 rt x 16 cs = 512 blocks = 2/CU,
// all co-resident in one dispatch round.
__global__ __launch_bounds__(256) void k_simsum(
    const __hip_bfloat16* __restrict__ pack, float* __restrict__ denom)
{
    const int tid  = threadIdx.x;
    const int lane = tid & 63;
    const int w    = tid >> 6;
    const int rt   = blockIdx.x >> 4;   // row tile [0,32)
    const int cs   = blockIdx.x & 15;   // col slab [0,16)
    const int q    = lane >> 4;         // quad 0..3
    const int l16  = lane & 15;

    // ---- persistent A fragments: wave's 64 rows x full K=128 (64 VGPRs) ----
    const int rowb = rt * 256 + w * 64;
    const __hip_bfloat16* Abase =
        pack + ((size_t)(rowb >> 4) * 4) * 512 + lane * 8;
    bf16x8 afrag[4][4];                  // [mt][ks]
    #pragma unroll
    for (int mt = 0; mt < 4; ++mt)
        #pragma unroll
        for (int ks = 0; ks < 4; ++ks)
            afrag[mt][ks] = *(const bf16x8*)(Abase + mt * 2048 + ks * 512);

    float rowsum[4][4];                  // [mt][r]
    #pragma unroll
    for (int mt = 0; mt < 4; ++mt)
        #pragma unroll
        for (int r = 0; r < 4; ++r) rowsum[mt][r] = 0.0f;

    const __hip_bfloat16* Bcol0 =
        pack + ((size_t)((cs * 512) >> 4) * 4) * 512 + lane * 8;

    auto loadB = [&](bf16x8 (&buf)[4][2], int hs) {
        const __hip_bfloat16* bp = Bcol0 + (size_t)hs * 4096;
        #pragma unroll
        for (int ks = 0; ks < 4; ++ks)
            #pragma unroll
            for (int nt = 0; nt < 2; ++nt)
                buf[ks][nt] = *(const bf16x8*)(bp + nt * 2048 + ks * 512);
    };

    auto mfma_step = [&](floatx4 (&acc)[4][2], bf16x8 (&buf)[4][2]) {
        #pragma unroll
        for (int mt = 0; mt < 4; ++mt)
            #pragma unroll
            for (int nt = 0; nt < 2; ++nt) {
                acc[mt][nt].x = 0.f; acc[mt][nt].y = 0.f;
                acc[mt][nt].z = 0.f; acc[mt][nt].w = 0.f;
            }
        #pragma unroll
        for (int ks = 0; ks < 4; ++ks)
            #pragma unroll
            for (int mt = 0; mt < 4; ++mt)
                #pragma unroll
                for (int nt = 0; nt < 2; ++nt)
                    acc[mt][nt] = __builtin_amdgcn_mfma_f32_16x16x32_bf16(
                        afrag[mt][ks], buf[ks][nt], acc[mt][nt], 0, 0, 0);
    };

    // fused epilogue: bare exp2 + row-sum.
    // C/D layout: col = l16, row = q*4 + r (m89/m91 verified)
    auto epi = [&](floatx4 (&acc)[4][2], int hs) {
        const int colb = cs * 512 + hs * 32;
        #pragma unroll
        for (int mt = 0; mt < 4; ++mt) {
            const int rowtb = rowb + mt * 16;
            #pragma unroll
            for (int nt = 0; nt < 2; ++nt) {
                const int coltb = colb + nt * 16;
                if (rowtb == coltb) {        // wave-uniform: diagonal tile
                    #pragma unroll
                    for (int r = 0; r < 4; ++r) {
                        const float e = __builtin_amdgcn_exp2f(acc[mt][nt][r]);
                        rowsum[mt][r] += (l16 == q * 4 + r) ? 0.0f : e;
                    }
                } else {
                    #pragma unroll
                    for (int r = 0; r < 4; ++r)
                        rowsum[mt][r] += __builtin_amdgcn_exp2f(acc[mt][nt][r]);
                }
            }
        }
    };

    // ---- main sweep: 16 half-steps; epilogue pipelined one step behind ----
    // Issue order per iteration: [load hs+2][MFMA hs+1][epi hs] — the epi
    // VALU executes under the matrix pipe's ~630-cyc occupancy of hs+1.
    bf16x8  bufA[4][2], bufB[4][2];
    floatx4 accA[4][2], accB[4][2];
    loadB(bufA, 0);
    loadB(bufB, 1);
    mfma_step(accA, bufA);
    for (int hs = 0; hs < 14; hs += 2) {
        loadB(bufA, hs + 2);
        mfma_step(accB, bufB);
        epi(accA, hs);
        loadB(bufB, hs + 3);
        mfma_step(accA, bufA);
        epi(accB, hs + 1);
    }
    mfma_step(accB, bufB);
    epi(accA, 14);
    epi(accB, 15);

    // ---- row-sum reduction: across the 16 lanes holding the same row ----
    #pragma unroll
    for (int mt = 0; mt < 4; ++mt)
        #pragma unroll
        for (int r = 0; r < 4; ++r) {
            float s = rowsum[mt][r];
            s += __shfl_xor(s, 1, 64);
            s += __shfl_xor(s, 2, 64);
            s += __shfl_xor(s, 4, 64);
            s += __shfl_xor(s, 8, 64);
            rowsum[mt][r] = s;
        }
    if (l16 == 0) {
        #pragma unroll
        for (int mt = 0; mt < 4; ++mt)
            #pragma unroll
            for (int r = 0; r < 4; ++r) {
                const int grow = rowb + mt * 16 + q * 4 + r;
                atomicAdd(&denom[grow], rowsum[mt][r]);
            }
    }
}

__global__ __launch_bounds__(1024) void k_finish(
    const float* __restrict__ denom, const float* __restrict__ pos,
    float* __restrict__ out)
{
    __shared__ float red[16];
    const int t = threadIdx.x;
    const int lane = t & 63, wv = t >> 6;
    float s = 0.0f;
    for (int i = t; i < NROWS; i += 1024) s += __logf(denom[i]);
    float p = 0.0f;
    for (int i = t; i < N_PAIRS; i += 1024) p += pos[i];
    float v = s - 4.0f * p;   // sum_i pos_i/T over 2N rows = 4 * sum_p cos_p
    #pragma unroll
    for (int off = 1; off < 64; off <<= 1) v += __shfl_xor(v, off, 64);
    if (lane == 0) red[wv] = v;
    __syncthreads();
    if (wv == 0) {
        float x = (lane < 16) ? red[lane] : 0.0f;
        #pragma unroll
        for (int off = 1; off < 16; off <<= 1) x += __shfl_xor(x, off, 64);
        if (lane == 0) out[0] = x / (float)NROWS;
    }
}

extern "C" void kernel_launch(void* const* d_in, const int* in_sizes, int n_in,
                              void* d_out, int out_size, void* d_ws, size_t ws_size,
                              hipStream_t stream) {
    const float* z1 = (const float*)d_in[0];
    const float* z2 = (const float*)d_in[1];
    float* out = (float*)d_out;

    char* ws = (char*)d_ws;
    __hip_bfloat16* pack = (__hip_bfloat16*)ws;                // 2 MB
    float* denom = (float*)(ws + (size_t)NROWS * ZDIM * 2);    // 32 KB
    float* pos   = denom + NROWS;                              // 16 KB

    k_normalize<<<N_PAIRS / 4, 256, 0, stream>>>(z1, z2, pack, pos, denom);
    k_simsum<<<512, 256, 0, stream>>>(pack, denom);
    k_finish<<<1, 1024, 0, stream>>>(denom, pos, out);
}